// Round 3
// baseline (1654.389 us; speedup 1.0000x reference)
//
#include <hip/hip_runtime.h>

#define N_NODES 50000
#define N_EDGES 1250000
#define EMBED 64
#define N_PAIRS (1024 * 100)
#define BSHIFT 7
#define BSIZE 128
#define NBUCK ((N_NODES + BSIZE - 1) / BSIZE)   // 391 buckets of 128 nodes

// ---------------- bucket histogram (LDS-staged) ----------------
__global__ __launch_bounds__(256) void hist_kernel(const int* __restrict__ dst,
                                                   int* __restrict__ hist) {
    __shared__ int hl[NBUCK];
    int t = threadIdx.x;
    for (int i = t; i < NBUCK; i += 256) hl[i] = 0;
    __syncthreads();
    int idx4 = blockIdx.x * 256 + t;
    if (idx4 < N_EDGES / 4) {
        int4 d = ((const int4*)dst)[idx4];
        atomicAdd(&hl[d.x >> BSHIFT], 1);
        atomicAdd(&hl[d.y >> BSHIFT], 1);
        atomicAdd(&hl[d.z >> BSHIFT], 1);
        atomicAdd(&hl[d.w >> BSHIFT], 1);
    }
    __syncthreads();
    for (int i = t; i < NBUCK; i += 256)
        if (hl[i]) atomicAdd(&hist[i], hl[i]);
}

// ---------------- scan 391 bucket counts (1 block, 512 threads) ----------------
__global__ __launch_bounds__(512) void bscan_kernel(const int* __restrict__ hist,
                                                    int* __restrict__ base,
                                                    int* __restrict__ cursor) {
    int t = threadIdx.x;
    int lane = t & 63, wid = t >> 6;
    int v = (t < NBUCK) ? hist[t] : 0;
    int incl = v;
    #pragma unroll
    for (int off = 1; off < 64; off <<= 1) {
        int o = __shfl_up(incl, off);
        if (lane >= off) incl += o;
    }
    __shared__ int ws[8];
    if (lane == 63) ws[wid] = incl;
    __syncthreads();
    if (t < 8) {
        int x = ws[t];
        #pragma unroll
        for (int off = 1; off < 8; off <<= 1) {
            int o = __shfl_up(x, off);
            if (t >= off) x += o;
        }
        ws[t] = x;
    }
    __syncthreads();
    int wbase = (wid > 0) ? ws[wid - 1] : 0;
    int ex = wbase + incl - v;
    if (t < NBUCK) { base[t] = ex; cursor[t] = ex; }
    if (t == NBUCK) base[NBUCK] = ex;   // total = N_EDGES
}

// ---------------- scatter edges into bucket-grouped packed array ----------------
// pairs[pos] = (dst_local << 17) | src   (src<2^17, dst_local<128)
__global__ __launch_bounds__(256) void scatter_kernel(const int* __restrict__ src,
                                                      const int* __restrict__ dst,
                                                      int* __restrict__ cursor,
                                                      unsigned int* __restrict__ pairs) {
    int idx4 = blockIdx.x * 256 + threadIdx.x;
    if (idx4 < N_EDGES / 4) {
        int4 s4 = ((const int4*)src)[idx4];
        int4 d4 = ((const int4*)dst)[idx4];
        int p0 = atomicAdd(&cursor[d4.x >> BSHIFT], 1);
        pairs[p0] = ((unsigned)(d4.x & (BSIZE - 1)) << 17) | (unsigned)s4.x;
        int p1 = atomicAdd(&cursor[d4.y >> BSHIFT], 1);
        pairs[p1] = ((unsigned)(d4.y & (BSIZE - 1)) << 17) | (unsigned)s4.y;
        int p2 = atomicAdd(&cursor[d4.z >> BSHIFT], 1);
        pairs[p2] = ((unsigned)(d4.z & (BSIZE - 1)) << 17) | (unsigned)s4.z;
        int p3 = atomicAdd(&cursor[d4.w >> BSHIFT], 1);
        pairs[p3] = ((unsigned)(d4.w & (BSIZE - 1)) << 17) | (unsigned)s4.w;
    }
}

// ---- fused bucket layer: gather + LDS atomic mean + GEMV(64x64) + tanh ----
__global__ __launch_bounds__(256) void layer_kernel(const float* __restrict__ hin,
                                                    float* __restrict__ hout,
                                                    const float* __restrict__ W,
                                                    const float* __restrict__ bvec,
                                                    const int* __restrict__ base,
                                                    const unsigned int* __restrict__ pairs) {
    __shared__ float agg[BSIZE][EMBED];   // 32 KB
    __shared__ float Wl[64][65];          // transposed, padded: Wl[d][j] = W[j][d]
    __shared__ int degL[BSIZE];
    int t = threadIdx.x;
    int wid = t >> 6, lane = t & 63;
    int g = lane >> 4, d16 = lane & 15;

    for (int i = t; i < BSIZE * EMBED; i += 256) ((float*)agg)[i] = 0.f;
    for (int i = t; i < 64 * 64; i += 256) Wl[i & 63][i >> 6] = W[i];
    if (t < BSIZE) degL[t] = 0;
    __syncthreads();

    int b = blockIdx.x;
    int start = base[b], end = base[b + 1];
    for (int p = start + wid * 8; p < end; p += 32) {
        int e0 = p + g, e1 = p + 4 + g;
        bool k0 = e0 < end, k1 = e1 < end;
        unsigned w0 = k0 ? pairs[e0] : 0u;
        unsigned w1 = k1 ? pairs[e1] : 0u;
        float4 v0 = {0.f, 0.f, 0.f, 0.f}, v1 = {0.f, 0.f, 0.f, 0.f};
        if (k0) v0 = ((const float4*)(hin + (size_t)(w0 & 0x1FFFFu) * EMBED))[d16];
        if (k1) v1 = ((const float4*)(hin + (size_t)(w1 & 0x1FFFFu) * EMBED))[d16];
        if (k0) {
            int dl = w0 >> 17;
            float* a = &agg[dl][d16 * 4];
            unsafeAtomicAdd(a + 0, v0.x); unsafeAtomicAdd(a + 1, v0.y);
            unsafeAtomicAdd(a + 2, v0.z); unsafeAtomicAdd(a + 3, v0.w);
            if (d16 == 0) atomicAdd(&degL[dl], 1);
        }
        if (k1) {
            int dl = w1 >> 17;
            float* a = &agg[dl][d16 * 4];
            unsafeAtomicAdd(a + 0, v1.x); unsafeAtomicAdd(a + 1, v1.y);
            unsafeAtomicAdd(a + 2, v1.z); unsafeAtomicAdd(a + 3, v1.w);
            if (d16 == 0) atomicAdd(&degL[dl], 1);
        }
    }
    __syncthreads();

    int nodes = min(BSIZE, N_NODES - (b << BSHIFT));
    float bj = bvec[lane];
    for (int n = wid; n < nodes; n += 4) {
        float dot = 0.f;
        #pragma unroll
        for (int d = 0; d < 64; ++d)
            dot += agg[n][d] * Wl[d][lane];
        int dg = degL[n];
        float inv = (dg > 0) ? 1.0f / (float)dg : 0.f;
        float x = bj + dot * inv;
        hout[((size_t)(b << BSHIFT) + n) * EMBED + lane] = tanhf(x);
    }
}

// ---------------- pair scoring: 16 lanes x float4 per pair ----------------
__global__ __launch_bounds__(256) void score_kernel(const float* __restrict__ h,
                                                    const int* __restrict__ ui,
                                                    const int* __restrict__ ii,
                                                    float* __restrict__ out) {
    int t = threadIdx.x;
    int idx = blockIdx.x * 16 + (t >> 4);
    int d16 = t & 15;
    int u = ui[idx];
    int v = ii[idx];
    float4 a = ((const float4*)(h + (size_t)u * EMBED))[d16];
    float4 b = ((const float4*)(h + (size_t)v * EMBED))[d16];
    float p = a.x * b.x + a.y * b.y + a.z * b.z + a.w * b.w;
    #pragma unroll
    for (int off = 8; off > 0; off >>= 1)
        p += __shfl_xor(p, off);
    if (d16 == 0) out[idx] = p;
}

extern "C" void kernel_launch(void* const* d_in, const int* in_sizes, int n_in,
                              void* d_out, int out_size, void* d_ws, size_t ws_size,
                              hipStream_t stream) {
    const float* emb = (const float*)d_in[0];
    const float* W0  = (const float*)d_in[1];
    const float* b0  = (const float*)d_in[2];
    const float* W1  = (const float*)d_in[3];
    const float* b1  = (const float*)d_in[4];
    const int* src   = (const int*)d_in[5];
    const int* dst   = (const int*)d_in[6];
    const int* ui    = (const int*)d_in[7];
    const int* ii    = (const int*)d_in[8];
    float* out = (float*)d_out;

    char* p = (char*)d_ws;
    auto alloc = [&](size_t bytes) {
        char* r = p;
        p += (bytes + 255) & ~(size_t)255;
        return r;
    };
    int* hist      = (int*)alloc(sizeof(int) * NBUCK);
    int* base      = (int*)alloc(sizeof(int) * (NBUCK + 1));
    int* cursor    = (int*)alloc(sizeof(int) * NBUCK);
    unsigned* pairs = (unsigned*)alloc(sizeof(unsigned) * N_EDGES);
    float* h1      = (float*)alloc(sizeof(float) * N_NODES * EMBED);
    float* h2      = (float*)alloc(sizeof(float) * N_NODES * EMBED);

    hipMemsetAsync(hist, 0, sizeof(int) * NBUCK, stream);
    int edge_blocks = (N_EDGES / 4 + 255) / 256;
    hist_kernel<<<edge_blocks, 256, 0, stream>>>(dst, hist);
    bscan_kernel<<<1, 512, 0, stream>>>(hist, base, cursor);
    scatter_kernel<<<edge_blocks, 256, 0, stream>>>(src, dst, cursor, pairs);
    layer_kernel<<<NBUCK, 256, 0, stream>>>(emb, h1, W0, b0, base, pairs);
    layer_kernel<<<NBUCK, 256, 0, stream>>>(h1, h2, W1, b1, base, pairs);
    score_kernel<<<N_PAIRS / 16, 256, 0, stream>>>(h2, ui, ii, out);
}

// Round 4
// 301.393 us; speedup vs baseline: 5.4891x; 5.4891x over previous
//
#include <hip/hip_runtime.h>

#define N_NODES 50000
#define N_EDGES 1250000
#define EMBED 64
#define N_PAIRS (1024 * 100)
#define BSHIFT 7
#define BSIZE 128
#define NBUCK 391      // ceil(50000/128)
#define CB 153         // scatter blocks (8192 edges each)
#define NBLKS 49       // node-scan blocks (1024 nodes each)
#define LDS_CAP 4096   // bucket edge capacity (mean 3200, sd 57 -> never exceeded)

// ---- pass 1: node degrees (global atomics, 50K counters) + per-block bucket hist ----
__global__ __launch_bounds__(1024) void deg_hist_kernel(const int* __restrict__ dst,
                                                        int* __restrict__ deg,
                                                        int* __restrict__ counts) {
    __shared__ int hl[NBUCK];
    int t = threadIdx.x, b = blockIdx.x;
    for (int i = t; i < NBUCK; i += 1024) hl[i] = 0;
    __syncthreads();
    #pragma unroll
    for (int rep = 0; rep < 2; ++rep) {
        int i4 = b * 2048 + rep * 1024 + t;
        if (i4 < N_EDGES / 4) {
            int4 d = ((const int4*)dst)[i4];
            atomicAdd(&deg[d.x], 1); atomicAdd(&hl[d.x >> BSHIFT], 1);
            atomicAdd(&deg[d.y], 1); atomicAdd(&hl[d.y >> BSHIFT], 1);
            atomicAdd(&deg[d.z], 1); atomicAdd(&hl[d.z >> BSHIFT], 1);
            atomicAdd(&deg[d.w], 1); atomicAdd(&hl[d.w >> BSHIFT], 1);
        }
    }
    __syncthreads();
    for (int i = t; i < NBUCK; i += 1024) counts[i * CB + b] = hl[i];
}

// ---- node-degree scan (3 kernels, from R2) -> row[] ----
__global__ __launch_bounds__(256) void blocksum_kernel(const int* __restrict__ deg,
                                                       int* __restrict__ bsum) {
    int t = threadIdx.x;
    int idx4 = blockIdx.x * 256 + t;
    int4 v = {0, 0, 0, 0};
    if (idx4 < N_NODES / 4) v = ((const int4*)deg)[idx4];
    int s = v.x + v.y + v.z + v.w;
    #pragma unroll
    for (int off = 32; off > 0; off >>= 1) s += __shfl_down(s, off);
    __shared__ int ws[4];
    int lane = t & 63, wid = t >> 6;
    if (lane == 0) ws[wid] = s;
    __syncthreads();
    if (t == 0) bsum[blockIdx.x] = ws[0] + ws[1] + ws[2] + ws[3];
}

__global__ __launch_bounds__(64) void bscan_kernel(const int* __restrict__ bsum,
                                                   int* __restrict__ boff,
                                                   int* __restrict__ rowend) {
    int t = threadIdx.x;
    int v = (t < NBLKS) ? bsum[t] : 0;
    int incl = v;
    #pragma unroll
    for (int off = 1; off < 64; off <<= 1) {
        int o = __shfl_up(incl, off);
        if (t >= off) incl += o;
    }
    if (t < NBLKS) boff[t] = incl - v;
    if (t == NBLKS - 1) rowend[0] = incl;   // row[N_NODES] = N_EDGES
}

__global__ __launch_bounds__(256) void scan2_kernel(const int* __restrict__ deg,
                                                    const int* __restrict__ boff,
                                                    int* __restrict__ row) {
    int t = threadIdx.x;
    int idx4 = blockIdx.x * 256 + t;
    bool ok = idx4 < N_NODES / 4;
    int4 v = {0, 0, 0, 0};
    if (ok) v = ((const int4*)deg)[idx4];
    int s = v.x + v.y + v.z + v.w;
    int lane = t & 63, wid = t >> 6;
    int incl = s;
    #pragma unroll
    for (int off = 1; off < 64; off <<= 1) {
        int o = __shfl_up(incl, off);
        if (lane >= off) incl += o;
    }
    __shared__ int ws[4];
    if (lane == 63) ws[wid] = incl;
    __syncthreads();
    int wbase = 0;
    for (int w = 0; w < wid; ++w) wbase += ws[w];
    int ex = wbase + (incl - s) + boff[blockIdx.x];
    if (ok) {
        int4 r;
        r.x = ex; r.y = ex + v.x; r.z = ex + v.x + v.y; r.w = ex + v.x + v.y + v.z;
        ((int4*)row)[idx4] = r;
    }
}

// ---- pass 2: per-(bucket,block) exclusive offsets; one wave per bucket ----
__global__ __launch_bounds__(64) void offs_kernel(const int* __restrict__ counts,
                                                  const int* __restrict__ row,
                                                  int* __restrict__ offs) {
    int k = blockIdx.x, lane = threadIdx.x;
    int carry = row[k * BSIZE];      // bucket base in edge space
    for (int tile = 0; tile < 3; ++tile) {
        int b = tile * 64 + lane;
        int v = (b < CB) ? counts[k * CB + b] : 0;
        int incl = v;
        #pragma unroll
        for (int off = 1; off < 64; off <<= 1) {
            int o = __shfl_up(incl, off);
            if (lane >= off) incl += o;
        }
        if (b < CB) offs[k * CB + b] = carry + incl - v;
        carry += __shfl(incl, 63);
    }
}

// ---- pass 3: scatter edges into bucket-grouped pairs (LDS cursors, no contention) ----
__global__ __launch_bounds__(1024) void scatter_kernel(const int* __restrict__ src,
                                                       const int* __restrict__ dst,
                                                       const int* __restrict__ offs,
                                                       unsigned int* __restrict__ pairs) {
    __shared__ int cur[NBUCK];
    int t = threadIdx.x, b = blockIdx.x;
    for (int i = t; i < NBUCK; i += 1024) cur[i] = offs[i * CB + b];
    __syncthreads();
    #pragma unroll
    for (int rep = 0; rep < 2; ++rep) {
        int i4 = b * 2048 + rep * 1024 + t;
        if (i4 < N_EDGES / 4) {
            int4 s4 = ((const int4*)src)[i4];
            int4 d4 = ((const int4*)dst)[i4];
            int p;
            p = atomicAdd(&cur[d4.x >> BSHIFT], 1);
            pairs[p] = ((unsigned)(d4.x & (BSIZE - 1)) << 16) | (unsigned)s4.x;
            p = atomicAdd(&cur[d4.y >> BSHIFT], 1);
            pairs[p] = ((unsigned)(d4.y & (BSIZE - 1)) << 16) | (unsigned)s4.y;
            p = atomicAdd(&cur[d4.z >> BSHIFT], 1);
            pairs[p] = ((unsigned)(d4.z & (BSIZE - 1)) << 16) | (unsigned)s4.z;
            p = atomicAdd(&cur[d4.w >> BSHIFT], 1);
            pairs[p] = ((unsigned)(d4.w & (BSIZE - 1)) << 16) | (unsigned)s4.w;
        }
    }
}

// ---- pass 4: per-bucket LDS sort -> node-level CSR col[], coalesced writes ----
__global__ __launch_bounds__(256) void bucketsort_kernel(const unsigned int* __restrict__ pairs,
                                                         const int* __restrict__ row,
                                                         int* __restrict__ col) {
    __shared__ int cur[BSIZE];
    __shared__ int staged[LDS_CAP];
    int k = blockIdx.x, t = threadIdx.x;
    int nstart = k * BSIZE;
    int nodes = min(BSIZE, N_NODES - nstart);
    int estart = row[nstart];
    int eend = row[nstart + nodes];
    int cnt = eend - estart;
    if (t < nodes) cur[t] = row[nstart + t] - estart;
    __syncthreads();
    if (cnt <= LDS_CAP) {
        for (int i = t; i < cnt; i += 256) {
            unsigned w = pairs[estart + i];
            int pos = atomicAdd(&cur[w >> 16], 1);
            staged[pos] = (int)(w & 0xFFFFu);
        }
        __syncthreads();
        for (int i = t; i < cnt; i += 256) col[estart + i] = staged[i];
    } else {   // statistically unreachable fallback
        for (int i = t; i < cnt; i += 256) {
            unsigned w = pairs[estart + i];
            int pos = atomicAdd(&cur[w >> 16], 1);
            col[estart + pos] = (int)(w & 0xFFFFu);
        }
    }
}

// ---- dense GEMV: g = h @ W^T  (linear commutes with mean) ----
__global__ __launch_bounds__(256) void gemv_kernel(const float* __restrict__ h,
                                                   const float* __restrict__ W,
                                                   float* __restrict__ g) {
    __shared__ float hL[64][64];
    __shared__ float Wl[64][65];   // Wl[d][j] = W[j][d]; pad -> conflict-free
    int t = threadIdx.x;
    int nstart = blockIdx.x * 64;
    int lane = t & 63, wid = t >> 6;
    for (int i = t; i < 4096; i += 256) Wl[i & 63][i >> 6] = W[i];
    int nrem = min(64, N_NODES - nstart);
    for (int i = t; i < nrem * 16; i += 256)
        ((float4*)hL)[i] = ((const float4*)(h + (size_t)nstart * EMBED))[i];
    __syncthreads();
    for (int n = wid; n < nrem; n += 4) {
        float x = 0.f;
        #pragma unroll
        for (int d = 0; d < 64; ++d)
            x += hL[n][d] * Wl[d][lane];
        g[(size_t)(nstart + n) * EMBED + lane] = x;
    }
}

// ---- gather-mean + bias + tanh; wave per node, 16 edges in flight ----
__global__ __launch_bounds__(256) void agg_kernel(const float* __restrict__ g,
                                                  const float* __restrict__ bias,
                                                  const int* __restrict__ row,
                                                  const int* __restrict__ col,
                                                  float* __restrict__ hout) {
    int t = threadIdx.x;
    int wid = t >> 6, lane = t & 63;
    int node = blockIdx.x * 4 + wid;   // grid exactly N_NODES/4
    int gg = lane >> 4, d16 = lane & 15;
    int start = row[node], end = row[node + 1];
    float4 bb = ((const float4*)bias)[d16];
    float4 acc = {0.f, 0.f, 0.f, 0.f};
    for (int e = start; e < end; e += 16) {
        int e0 = e + gg, e1 = e + 4 + gg, e2 = e + 8 + gg, e3 = e + 12 + gg;
        bool k0 = e0 < end, k1 = e1 < end, k2 = e2 < end, k3 = e3 < end;
        int s0 = k0 ? col[e0] : 0;
        int s1 = k1 ? col[e1] : 0;
        int s2 = k2 ? col[e2] : 0;
        int s3 = k3 ? col[e3] : 0;
        float4 v0 = {0,0,0,0}, v1 = {0,0,0,0}, v2 = {0,0,0,0}, v3 = {0,0,0,0};
        if (k0) v0 = ((const float4*)(g + (size_t)s0 * EMBED))[d16];
        if (k1) v1 = ((const float4*)(g + (size_t)s1 * EMBED))[d16];
        if (k2) v2 = ((const float4*)(g + (size_t)s2 * EMBED))[d16];
        if (k3) v3 = ((const float4*)(g + (size_t)s3 * EMBED))[d16];
        acc.x += (v0.x + v1.x) + (v2.x + v3.x);
        acc.y += (v0.y + v1.y) + (v2.y + v3.y);
        acc.z += (v0.z + v1.z) + (v2.z + v3.z);
        acc.w += (v0.w + v1.w) + (v2.w + v3.w);
    }
    #pragma unroll
    for (int off = 16; off < 64; off <<= 1) {
        acc.x += __shfl_xor(acc.x, off);
        acc.y += __shfl_xor(acc.y, off);
        acc.z += __shfl_xor(acc.z, off);
        acc.w += __shfl_xor(acc.w, off);
    }
    int dg = end - start;
    float inv = (dg > 0) ? 1.0f / (float)dg : 0.f;
    if (gg == 0) {
        float4 o;
        o.x = tanhf(acc.x * inv + bb.x);
        o.y = tanhf(acc.y * inv + bb.y);
        o.z = tanhf(acc.z * inv + bb.z);
        o.w = tanhf(acc.w * inv + bb.w);
        ((float4*)(hout + (size_t)node * EMBED))[d16] = o;
    }
}

// ---- pair scoring: 16 lanes x float4 per pair ----
__global__ __launch_bounds__(256) void score_kernel(const float* __restrict__ h,
                                                    const int* __restrict__ ui,
                                                    const int* __restrict__ ii,
                                                    float* __restrict__ out) {
    int t = threadIdx.x;
    int idx = blockIdx.x * 16 + (t >> 4);
    int d16 = t & 15;
    int u = ui[idx];
    int v = ii[idx];
    float4 a = ((const float4*)(h + (size_t)u * EMBED))[d16];
    float4 b = ((const float4*)(h + (size_t)v * EMBED))[d16];
    float p = a.x * b.x + a.y * b.y + a.z * b.z + a.w * b.w;
    #pragma unroll
    for (int off = 8; off > 0; off >>= 1)
        p += __shfl_xor(p, off);
    if (d16 == 0) out[idx] = p;
}

extern "C" void kernel_launch(void* const* d_in, const int* in_sizes, int n_in,
                              void* d_out, int out_size, void* d_ws, size_t ws_size,
                              hipStream_t stream) {
    const float* emb = (const float*)d_in[0];
    const float* W0  = (const float*)d_in[1];
    const float* b0  = (const float*)d_in[2];
    const float* W1  = (const float*)d_in[3];
    const float* b1  = (const float*)d_in[4];
    const int* src   = (const int*)d_in[5];
    const int* dst   = (const int*)d_in[6];
    const int* ui    = (const int*)d_in[7];
    const int* ii    = (const int*)d_in[8];
    float* out = (float*)d_out;

    char* p = (char*)d_ws;
    auto alloc = [&](size_t bytes) {
        char* r = p;
        p += (bytes + 255) & ~(size_t)255;
        return r;
    };
    int* deg       = (int*)alloc(sizeof(int) * N_NODES);
    int* row       = (int*)alloc(sizeof(int) * (N_NODES + 1));
    int* counts    = (int*)alloc(sizeof(int) * NBUCK * CB);
    int* offs      = (int*)alloc(sizeof(int) * NBUCK * CB);
    int* bsum      = (int*)alloc(sizeof(int) * NBLKS);
    int* boff      = (int*)alloc(sizeof(int) * NBLKS);
    unsigned* pairs = (unsigned*)alloc(sizeof(unsigned) * N_EDGES);
    int* col       = (int*)alloc(sizeof(int) * N_EDGES);
    float* gbuf    = (float*)alloc(sizeof(float) * N_NODES * EMBED);
    float* hbuf    = (float*)alloc(sizeof(float) * N_NODES * EMBED);

    hipMemsetAsync(deg, 0, sizeof(int) * N_NODES, stream);
    deg_hist_kernel<<<CB, 1024, 0, stream>>>(dst, deg, counts);
    blocksum_kernel<<<NBLKS, 256, 0, stream>>>(deg, bsum);
    bscan_kernel<<<1, 64, 0, stream>>>(bsum, boff, row + N_NODES);
    scan2_kernel<<<NBLKS, 256, 0, stream>>>(deg, boff, row);
    offs_kernel<<<NBUCK, 64, 0, stream>>>(counts, row, offs);
    scatter_kernel<<<CB, 1024, 0, stream>>>(src, dst, offs, pairs);
    bucketsort_kernel<<<NBUCK, 256, 0, stream>>>(pairs, row, col);
    // layer 1: g = emb @ W0^T; h = tanh(mean(g[src]) + b0)
    gemv_kernel<<<(N_NODES + 63) / 64, 256, 0, stream>>>(emb, W0, gbuf);
    agg_kernel<<<N_NODES / 4, 256, 0, stream>>>(gbuf, b0, row, col, hbuf);
    // layer 2
    gemv_kernel<<<(N_NODES + 63) / 64, 256, 0, stream>>>(hbuf, W1, gbuf);
    agg_kernel<<<N_NODES / 4, 256, 0, stream>>>(gbuf, b1, row, col, hbuf);
    score_kernel<<<N_PAIRS / 16, 256, 0, stream>>>(hbuf, ui, ii, out);
}

// Round 6
// 249.575 us; speedup vs baseline: 6.6288x; 1.2076x over previous
//
#include <hip/hip_runtime.h>

#define N_NODES 50000
#define N_EDGES 1250000
#define EMBED 64
#define N_PAIRS (1024 * 100)
#define BSHIFT 7
#define BSIZE 128
#define NBUCK 391      // ceil(50000/128)
#define CB 153         // edge blocks (8192 edges each)
#define LDS_CAP 4096   // bucket edge capacity (mean 3200, sd 57)

// ---- pass 1: per-block bucket histogram (LDS only, no global atomics) ----
// counts layout: counts[block][bucket] (transposed -> coalesced everywhere)
__global__ __launch_bounds__(1024) void hist_kernel(const int* __restrict__ dst,
                                                    int* __restrict__ counts) {
    __shared__ int hl[NBUCK];
    int t = threadIdx.x, b = blockIdx.x;
    for (int i = t; i < NBUCK; i += 1024) hl[i] = 0;
    __syncthreads();
    #pragma unroll
    for (int rep = 0; rep < 2; ++rep) {
        int i4 = b * 2048 + rep * 1024 + t;
        if (i4 < N_EDGES / 4) {
            int4 d = ((const int4*)dst)[i4];
            atomicAdd(&hl[d.x >> BSHIFT], 1);
            atomicAdd(&hl[d.y >> BSHIFT], 1);
            atomicAdd(&hl[d.z >> BSHIFT], 1);
            atomicAdd(&hl[d.w >> BSHIFT], 1);
        }
    }
    __syncthreads();
    for (int i = t; i < NBUCK; i += 1024) counts[b * NBUCK + i] = hl[i];
}

// ---- pass 2 (1 block): bucket totals -> base[] scan -> per-(block,bucket) offs ----
__global__ __launch_bounds__(512) void prep_kernel(const int* __restrict__ counts,
                                                   int* __restrict__ offs,
                                                   int* __restrict__ base) {
    __shared__ int ws[8];
    int t = threadIdx.x, lane = t & 63, wid = t >> 6;
    int tot = 0;
    if (t < NBUCK)
        for (int b = 0; b < CB; ++b) tot += counts[b * NBUCK + t];   // coalesced
    int incl = tot;
    #pragma unroll
    for (int off = 1; off < 64; off <<= 1) {
        int o = __shfl_up(incl, off);
        if (lane >= off) incl += o;
    }
    if (lane == 63) ws[wid] = incl;
    __syncthreads();
    if (t < 8) {
        int x = ws[t];
        #pragma unroll
        for (int off = 1; off < 8; off <<= 1) {
            int o = __shfl_up(x, off);
            if (t >= off) x += o;
        }
        ws[t] = x;
    }
    __syncthreads();
    int ex = ((wid > 0) ? ws[wid - 1] : 0) + incl - tot;
    if (t < NBUCK) base[t] = ex;
    if (t == 0) base[NBUCK] = N_EDGES;
    // pass 2: column-wise running offsets (coalesced across t each step)
    if (t < NBUCK) {
        int run = ex;
        for (int b = 0; b < CB; ++b) {
            offs[b * NBUCK + t] = run;
            run += counts[b * NBUCK + t];
        }
    }
}

// ---- pass 3: scatter edges into bucket-grouped pairs (LDS cursors) ----
__global__ __launch_bounds__(1024) void scatter_kernel(const int* __restrict__ src,
                                                       const int* __restrict__ dst,
                                                       const int* __restrict__ offs,
                                                       unsigned int* __restrict__ pairs) {
    __shared__ int cur[NBUCK];
    int t = threadIdx.x, b = blockIdx.x;
    for (int i = t; i < NBUCK; i += 1024) cur[i] = offs[b * NBUCK + i];
    __syncthreads();
    #pragma unroll
    for (int rep = 0; rep < 2; ++rep) {
        int i4 = b * 2048 + rep * 1024 + t;
        if (i4 < N_EDGES / 4) {
            int4 s4 = ((const int4*)src)[i4];
            int4 d4 = ((const int4*)dst)[i4];
            int p;
            p = atomicAdd(&cur[d4.x >> BSHIFT], 1);
            pairs[p] = ((unsigned)(d4.x & (BSIZE - 1)) << 16) | (unsigned)s4.x;
            p = atomicAdd(&cur[d4.y >> BSHIFT], 1);
            pairs[p] = ((unsigned)(d4.y & (BSIZE - 1)) << 16) | (unsigned)s4.y;
            p = atomicAdd(&cur[d4.z >> BSHIFT], 1);
            pairs[p] = ((unsigned)(d4.z & (BSIZE - 1)) << 16) | (unsigned)s4.z;
            p = atomicAdd(&cur[d4.w >> BSHIFT], 1);
            pairs[p] = ((unsigned)(d4.w & (BSIZE - 1)) << 16) | (unsigned)s4.w;
        }
    }
}

// ---- pass 4: per-bucket LDS sort -> row[] + coalesced col[] ----
__global__ __launch_bounds__(256) void bucketsort_kernel(const unsigned int* __restrict__ pairs,
                                                         const int* __restrict__ base,
                                                         int* __restrict__ row,
                                                         int* __restrict__ col) {
    __shared__ unsigned ebuf[LDS_CAP];
    __shared__ int staged[LDS_CAP];
    __shared__ int hist[BSIZE];
    __shared__ int cur[BSIZE];
    __shared__ int wtot;
    int k = blockIdx.x, t = threadIdx.x;
    int lane = t & 63, wid = t >> 6;
    int nstart = k * BSIZE;
    int nodes = min(BSIZE, N_NODES - nstart);
    int estart = base[k], eend = base[k + 1];
    int cnt = eend - estart;
    if (t < BSIZE) hist[t] = 0;
    __syncthreads();
    if (cnt <= LDS_CAP) {
        for (int i = t; i < cnt; i += 256) {
            unsigned w = pairs[estart + i];
            ebuf[i] = w;
            atomicAdd(&hist[w >> 16], 1);
        }
        __syncthreads();
        if (t < BSIZE) {                       // scan 128 counters (2 waves)
            int v = hist[t];
            int incl = v;
            #pragma unroll
            for (int off = 1; off < 64; off <<= 1) {
                int o = __shfl_up(incl, off);
                if (lane >= off) incl += o;
            }
            if (t == 63) wtot = incl;
            __syncthreads();
            int ex = incl - v + ((wid == 1) ? wtot : 0);
            cur[t] = ex;
            if (t < nodes) row[nstart + t] = estart + ex;
        } else {
            __syncthreads();
        }
        if (k == NBUCK - 1 && t == 0) row[N_NODES] = N_EDGES;
        __syncthreads();
        for (int i = t; i < cnt; i += 256) {
            unsigned w = ebuf[i];
            int pos = atomicAdd(&cur[w >> 16], 1);
            staged[pos] = (int)(w & 0xFFFFu);
        }
        __syncthreads();
        for (int i = t; i < cnt; i += 256) col[estart + i] = staged[i];
    } else {   // statistically unreachable fallback (no LDS staging)
        for (int i = t; i < cnt; i += 256)
            atomicAdd(&hist[pairs[estart + i] >> 16], 1);
        __syncthreads();
        if (t < BSIZE) {
            int v = hist[t];
            int incl = v;
            #pragma unroll
            for (int off = 1; off < 64; off <<= 1) {
                int o = __shfl_up(incl, off);
                if (lane >= off) incl += o;
            }
            if (t == 63) wtot = incl;
            __syncthreads();
            int ex = incl - v + ((wid == 1) ? wtot : 0);
            cur[t] = ex;
            if (t < nodes) row[nstart + t] = estart + ex;
        } else {
            __syncthreads();
        }
        if (k == NBUCK - 1 && t == 0) row[N_NODES] = N_EDGES;
        __syncthreads();
        for (int i = t; i < cnt; i += 256) {
            unsigned w = pairs[estart + i];
            int pos = atomicAdd(&cur[w >> 16], 1);
            col[estart + pos] = (int)(w & 0xFFFFu);
        }
    }
}

// ---- dense GEMV: g = h @ W^T (linear commutes with mean) ----
__global__ __launch_bounds__(256) void gemv_kernel(const float* __restrict__ h,
                                                   const float* __restrict__ W,
                                                   float* __restrict__ g) {
    __shared__ float hL[64][64];
    __shared__ float Wl[64][65];   // Wl[d][j] = W[j][d]
    int t = threadIdx.x;
    int nstart = blockIdx.x * 64;
    int lane = t & 63, wid = t >> 6;
    for (int i = t; i < 4096; i += 256) Wl[i & 63][i >> 6] = W[i];
    int nrem = min(64, N_NODES - nstart);
    for (int i = t; i < nrem * 16; i += 256)
        ((float4*)hL)[i] = ((const float4*)(h + (size_t)nstart * EMBED))[i];
    __syncthreads();
    for (int n = wid; n < nrem; n += 4) {
        float x = 0.f;
        #pragma unroll
        for (int d = 0; d < 64; ++d)
            x += hL[n][d] * Wl[d][lane];
        g[(size_t)(nstart + n) * EMBED + lane] = x;
    }
}

// ---- gather-mean + bias + tanh; wave per node, 16 edges in flight ----
__global__ __launch_bounds__(256) void agg_kernel(const float* __restrict__ g,
                                                  const float* __restrict__ bias,
                                                  const int* __restrict__ row,
                                                  const int* __restrict__ col,
                                                  float* __restrict__ hout) {
    int t = threadIdx.x;
    int wid = t >> 6, lane = t & 63;
    int node = blockIdx.x * 4 + wid;   // grid exactly N_NODES/4
    int gg = lane >> 4, d16 = lane & 15;
    int start = row[node], end = row[node + 1];
    float4 bb = ((const float4*)bias)[d16];
    float4 acc = {0.f, 0.f, 0.f, 0.f};
    for (int e = start; e < end; e += 16) {
        int e0 = e + gg, e1 = e + 4 + gg, e2 = e + 8 + gg, e3 = e + 12 + gg;
        bool k0 = e0 < end, k1 = e1 < end, k2 = e2 < end, k3 = e3 < end;
        int s0 = k0 ? col[e0] : 0;
        int s1 = k1 ? col[e1] : 0;
        int s2 = k2 ? col[e2] : 0;
        int s3 = k3 ? col[e3] : 0;
        float4 v0 = {0,0,0,0}, v1 = {0,0,0,0}, v2 = {0,0,0,0}, v3 = {0,0,0,0};
        if (k0) v0 = ((const float4*)(g + (size_t)s0 * EMBED))[d16];
        if (k1) v1 = ((const float4*)(g + (size_t)s1 * EMBED))[d16];
        if (k2) v2 = ((const float4*)(g + (size_t)s2 * EMBED))[d16];
        if (k3) v3 = ((const float4*)(g + (size_t)s3 * EMBED))[d16];
        acc.x += (v0.x + v1.x) + (v2.x + v3.x);
        acc.y += (v0.y + v1.y) + (v2.y + v3.y);
        acc.z += (v0.z + v1.z) + (v2.z + v3.z);
        acc.w += (v0.w + v1.w) + (v2.w + v3.w);
    }
    #pragma unroll
    for (int off = 16; off < 64; off <<= 1) {
        acc.x += __shfl_xor(acc.x, off);
        acc.y += __shfl_xor(acc.y, off);
        acc.z += __shfl_xor(acc.z, off);
        acc.w += __shfl_xor(acc.w, off);
    }
    int dg = end - start;
    float inv = (dg > 0) ? 1.0f / (float)dg : 0.f;
    if (gg == 0) {
        float4 o;
        o.x = tanhf(acc.x * inv + bb.x);
        o.y = tanhf(acc.y * inv + bb.y);
        o.z = tanhf(acc.z * inv + bb.z);
        o.w = tanhf(acc.w * inv + bb.w);
        ((float4*)(hout + (size_t)node * EMBED))[d16] = o;
    }
}

// ---- pair scoring: 16 lanes x float4 per pair ----
__global__ __launch_bounds__(256) void score_kernel(const float* __restrict__ h,
                                                    const int* __restrict__ ui,
                                                    const int* __restrict__ ii,
                                                    float* __restrict__ out) {
    int t = threadIdx.x;
    int idx = blockIdx.x * 16 + (t >> 4);
    int d16 = t & 15;
    int u = ui[idx];
    int v = ii[idx];
    float4 a = ((const float4*)(h + (size_t)u * EMBED))[d16];
    float4 b = ((const float4*)(h + (size_t)v * EMBED))[d16];
    float p = a.x * b.x + a.y * b.y + a.z * b.z + a.w * b.w;
    #pragma unroll
    for (int off = 8; off > 0; off >>= 1)
        p += __shfl_xor(p, off);
    if (d16 == 0) out[idx] = p;
}

extern "C" void kernel_launch(void* const* d_in, const int* in_sizes, int n_in,
                              void* d_out, int out_size, void* d_ws, size_t ws_size,
                              hipStream_t stream) {
    const float* emb = (const float*)d_in[0];
    const float* W0  = (const float*)d_in[1];
    const float* b0  = (const float*)d_in[2];
    const float* W1  = (const float*)d_in[3];
    const float* b1  = (const float*)d_in[4];
    const int* src   = (const int*)d_in[5];
    const int* dst   = (const int*)d_in[6];
    const int* ui    = (const int*)d_in[7];
    const int* ii    = (const int*)d_in[8];
    float* out = (float*)d_out;

    char* p = (char*)d_ws;
    auto alloc = [&](size_t bytes) {
        char* r = p;
        p += (bytes + 255) & ~(size_t)255;
        return r;
    };
    int* counts     = (int*)alloc(sizeof(int) * NBUCK * CB);
    int* offs       = (int*)alloc(sizeof(int) * NBUCK * CB);
    int* base       = (int*)alloc(sizeof(int) * (NBUCK + 1));
    int* row        = (int*)alloc(sizeof(int) * (N_NODES + 1));
    unsigned* pairs = (unsigned*)alloc(sizeof(unsigned) * N_EDGES);
    int* col        = (int*)alloc(sizeof(int) * N_EDGES);
    float* gbuf     = (float*)alloc(sizeof(float) * N_NODES * EMBED);
    float* hbuf     = (float*)alloc(sizeof(float) * N_NODES * EMBED);

    hist_kernel<<<CB, 1024, 0, stream>>>(dst, counts);
    prep_kernel<<<1, 512, 0, stream>>>(counts, offs, base);
    scatter_kernel<<<CB, 1024, 0, stream>>>(src, dst, offs, pairs);
    bucketsort_kernel<<<NBUCK, 256, 0, stream>>>(pairs, base, row, col);
    // layer 1: g = emb @ W0^T; h = tanh(mean(g[src]) + b0)
    gemv_kernel<<<(N_NODES + 63) / 64, 256, 0, stream>>>(emb, W0, gbuf);
    agg_kernel<<<N_NODES / 4, 256, 0, stream>>>(gbuf, b0, row, col, hbuf);
    // layer 2 (reuse buffers)
    gemv_kernel<<<(N_NODES + 63) / 64, 256, 0, stream>>>(hbuf, W1, gbuf);
    agg_kernel<<<N_NODES / 4, 256, 0, stream>>>(gbuf, b1, row, col, hbuf);
    score_kernel<<<N_PAIRS / 16, 256, 0, stream>>>(hbuf, ui, ii, out);
}